// Round 3
// baseline (256.569 us; speedup 1.0000x reference)
//
#include <hip/hip_runtime.h>
#include <hip/hip_bf16.h>

// Problem constants
#define B 64
#define D 25000
#define K 16
#define H 128
#define E 256
#define Z 32
#define DTILE 10
#define NBLK (D / DTILE)      // 2500 blocks -> 10000 waves (~39/CU demanded)
#define NREP 64               // replica accumulators
#define XSTR 65               // padded stride, conflict-free strided writes
#define MSTR 68               // padded stride, %4==0 for float4 reads

#define REPF (NREP * B * K)   // 65536 floats = 256 KB

typedef __attribute__((ext_vector_type(8))) short short8;
typedef __attribute__((ext_vector_type(4))) float f32x4;

__device__ __forceinline__ unsigned short f2bf(float f) {
    union { float f; unsigned u; } v; v.f = f;
    unsigned u = v.u + 0x7FFF + ((v.u >> 16) & 1);
    return (unsigned short)(u >> 16);
}
__device__ __forceinline__ float bf2f(unsigned short s) {
    union { unsigned u; float f; } v; v.u = (unsigned)s << 16;
    return v.f;
}
// single-instruction packed f32->bf16 (lo=a, hi=b)
__device__ __forceinline__ unsigned cvt_pk_bf16(float a, float b) {
    unsigned r;
    asm("v_cvt_pk_bf16_f32 %0, %1, %2" : "=v"(r) : "v"(a), "v"(b));
    return r;
}

// prep: block 0 converts W2 -> fragment-ordered bf16 hi/lo tables;
// blocks 1..NREP zero the replica accumulators.
__global__ __launch_bounds__(256) void prep_kernel(
    const float* __restrict__ W2, float* __restrict__ rep,
    unsigned short* __restrict__ hi, unsigned short* __restrict__ lo)
{
    const int t = threadIdx.x;
    if (blockIdx.x == 0) {
        for (int i = t; i < H * K; i += 256) {
            // i = ((s*4+g)*16+n)*8+j
            int j = i & 7, n = (i >> 3) & 15, g = (i >> 7) & 3, s = i >> 9;
            int k = s * 32 + g * 8 + j;
            float w = W2[k * K + n];
            unsigned short h = f2bf(w);
            hi[i] = h;
            lo[i] = f2bf(w - bf2f(h));
        }
    } else {
        int r = blockIdx.x - 1;
        for (int i = t; i < B * K; i += 256) rep[r * B * K + i] = 0.f;
    }
}

// main: per (b,d): h1 = relu(x*w0 + G_d) [VALU], h2 = relu(h1@W2+b2) [2x bf16 MFMA],
// c += mask*h2 [fp32 epilogue, replica atomics]
__global__ __launch_bounds__(256, 8) void partial_main_kernel(
    const float* __restrict__ x, const int* __restrict__ mask,
    const float* __restrict__ feat_emb, const float* __restrict__ feat_bias,
    const float* __restrict__ W1, const float* __restrict__ b1,
    const float* __restrict__ b2, float* __restrict__ rep,
    const unsigned short* __restrict__ hi, const unsigned short* __restrict__ lo)
{
    __shared__ __align__(16) float sG[DTILE * H];     // 1280 f
    __shared__ __align__(16) float sX[DTILE * XSTR];  // 650 f
    __shared__ __align__(16) float sMf[DTILE * MSTR]; // 680 f

    const int t    = threadIdx.x;
    const int d0   = blockIdx.x * DTILE;
    const int lane = t & 63;
    const int wv   = t >> 6;
    const int g    = lane >> 4;
    const int n    = lane & 15;

    // stage x/mask transposed into LDS (coalesced-ish global reads)
    for (int i = t; i < DTILE * B; i += 256) {
        int bb = i / DTILE, dd = i - bb * DTILE;
        sX[dd * XSTR + bb]  = x[bb * D + d0 + dd];
        sMf[dd * MSTR + bb] = (float)mask[bb * D + d0 + dd];
    }
    // G tile: G[dd][h] = feat_emb[d]@W1[1:17] + feat_bias[d]*W1[17] + b1  (L2-hit weights)
    for (int i = t; i < DTILE * H; i += 256) {
        int dd = i >> 7, h = i & (H - 1);
        int d = d0 + dd;
        float acc = fmaf(feat_bias[d], W1[17 * H + h], b1[h]);
        #pragma unroll
        for (int k = 0; k < K; ++k)
            acc = fmaf(feat_emb[d * K + k], W1[(1 + k) * H + h], acc);
        sG[i] = acc;
    }

    // per-lane W2 fragments (prepped) and w0 registers (no LDS dependence)
    short8 Bf1[4], Bf2[4];
    #pragma unroll
    for (int s = 0; s < 4; ++s) {
        Bf1[s] = *(const short8*)(hi + (((s * 4 + g) * 16 + n) << 3));
        Bf2[s] = *(const short8*)(lo + (((s * 4 + g) * 16 + n) << 3));
    }
    float w0r[4][8];
    #pragma unroll
    for (int s = 0; s < 4; ++s) {
        const float4* wp = (const float4*)&W1[s * 32 + g * 8];
        float4 a0 = wp[0], a1 = wp[1];
        w0r[s][0] = a0.x; w0r[s][1] = a0.y; w0r[s][2] = a0.z; w0r[s][3] = a0.w;
        w0r[s][4] = a1.x; w0r[s][5] = a1.y; w0r[s][6] = a1.z; w0r[s][7] = a1.w;
    }
    const float b2n = b2[n];
    __syncthreads();

    // hot loop
    f32x4 cacc = {0.f, 0.f, 0.f, 0.f};
    const int xoff = wv * 16 + n;
    const int moff = wv * 16 + g * 4;

    for (int dd = 0; dd < DTILE; ++dd) {
        const float xv = sX[dd * XSTR + xoff];
        f32x4 c1 = {0.f, 0.f, 0.f, 0.f};
        f32x4 c2 = {0.f, 0.f, 0.f, 0.f};
        #pragma unroll
        for (int s = 0; s < 4; ++s) {
            const float4* gp = (const float4*)&sG[dd * H + s * 32 + g * 8];
            const float4 g0 = gp[0], g1 = gp[1];
            float h0 = fmaxf(fmaf(xv, w0r[s][0], g0.x), 0.f);
            float h1 = fmaxf(fmaf(xv, w0r[s][1], g0.y), 0.f);
            float h2 = fmaxf(fmaf(xv, w0r[s][2], g0.z), 0.f);
            float h3 = fmaxf(fmaf(xv, w0r[s][3], g0.w), 0.f);
            float h4 = fmaxf(fmaf(xv, w0r[s][4], g1.x), 0.f);
            float h5 = fmaxf(fmaf(xv, w0r[s][5], g1.y), 0.f);
            float h6 = fmaxf(fmaf(xv, w0r[s][6], g1.z), 0.f);
            float h7 = fmaxf(fmaf(xv, w0r[s][7], g1.w), 0.f);
            union { short8 v; unsigned u[4]; } a;
            a.u[0] = cvt_pk_bf16(h0, h1);
            a.u[1] = cvt_pk_bf16(h2, h3);
            a.u[2] = cvt_pk_bf16(h4, h5);
            a.u[3] = cvt_pk_bf16(h6, h7);
            c1 = __builtin_amdgcn_mfma_f32_16x16x32_bf16(a.v, Bf1[s], c1, 0, 0, 0);
            c2 = __builtin_amdgcn_mfma_f32_16x16x32_bf16(a.v, Bf2[s], c2, 0, 0, 0);
        }
        const float4 mv = *(const float4*)&sMf[dd * MSTR + moff];
        float p0 = c1[0] + c2[0] + b2n;
        float p1 = c1[1] + c2[1] + b2n;
        float p2 = c1[2] + c2[2] + b2n;
        float p3 = c1[3] + c2[3] + b2n;
        cacc[0] = fmaf(mv.x, fmaxf(p0, 0.f), cacc[0]);
        cacc[1] = fmaf(mv.y, fmaxf(p1, 0.f), cacc[1]);
        cacc[2] = fmaf(mv.z, fmaxf(p2, 0.f), cacc[2]);
        cacc[3] = fmaf(mv.w, fmaxf(p3, 0.f), cacc[3]);
    }

    float* crep = rep + (size_t)(blockIdx.x & (NREP - 1)) * (B * K);
    #pragma unroll
    for (int r = 0; r < 4; ++r)
        atomicAdd(&crep[(moff + r) * K + n], cacc[r]);
}

// enc: reduce replicas -> c[b][:], then 16->256->64 MLP. one block per sample.
__global__ __launch_bounds__(256) void partial_enc_kernel(
    const float* __restrict__ rep, const float* __restrict__ We1,
    const float* __restrict__ be1, const float* __restrict__ We2,
    const float* __restrict__ be2, float* __restrict__ out)
{
    const int b = blockIdx.x;
    const int t = threadIdx.x;
    __shared__ float sc[K];
    __shared__ float st1[E];
    __shared__ float red[256];

    {   // replica reduction
        const int k = t & 15, grp = t >> 4;
        float a = 0.f;
        #pragma unroll
        for (int r = grp; r < NREP; r += 16)
            a += rep[r * (B * K) + b * K + k];
        red[t] = a;
    }
    __syncthreads();
    if (t < K) {
        float s2 = 0.f;
        #pragma unroll
        for (int q = 0; q < 16; ++q) s2 += red[q * 16 + t];
        sc[t] = s2;
    }
    __syncthreads();

    {
        float acc = be1[t];
        #pragma unroll
        for (int k = 0; k < K; ++k)
            acc = fmaf(sc[k], We1[k * E + t], acc);
        st1[t] = fmaxf(acc, 0.f);
    }
    __syncthreads();

    const int j = t & 63, seg = t >> 6;
    float acc = 0.f;
    #pragma unroll 4
    for (int e = seg * 64; e < seg * 64 + 64; ++e)
        acc = fmaf(st1[e], We2[e * 64 + j], acc);
    red[t] = acc;
    __syncthreads();

    if (t < 64) {
        float v = red[j] + red[64 + j] + red[128 + j] + red[192 + j] + be2[j];
        if (j < Z) out[b * Z + j] = v;                 // mu
        else       out[B * Z + b * Z + (j - Z)] = v;   // logvar
    }
}

extern "C" void kernel_launch(void* const* d_in, const int* in_sizes, int n_in,
                              void* d_out, int out_size, void* d_ws, size_t ws_size,
                              hipStream_t stream) {
    const float* x         = (const float*)d_in[0];
    const int*   mask      = (const int*)  d_in[1];
    const float* feat_emb  = (const float*)d_in[2];
    const float* feat_bias = (const float*)d_in[3];
    const float* W1        = (const float*)d_in[4];
    const float* b1        = (const float*)d_in[5];
    const float* W2        = (const float*)d_in[6];
    const float* b2        = (const float*)d_in[7];
    const float* We1       = (const float*)d_in[8];
    const float* be1       = (const float*)d_in[9];
    const float* We2       = (const float*)d_in[10];
    const float* be2       = (const float*)d_in[11];

    // ws layout: replicas (256 KB) | W2 bf16 hi (4 KB) | W2 bf16 lo (4 KB)
    float* rep = (float*)d_ws;
    unsigned short* hi = (unsigned short*)((char*)d_ws + (size_t)REPF * 4);
    unsigned short* lo = hi + H * K;

    prep_kernel<<<1 + NREP, 256, 0, stream>>>(W2, rep, hi, lo);
    partial_main_kernel<<<NBLK, 256, 0, stream>>>(
        x, mask, feat_emb, feat_bias, W1, b1, b2, rep, hi, lo);
    partial_enc_kernel<<<B, 256, 0, stream>>>(
        rep, We1, be1, We2, be2, (float*)d_out);
}

// Round 6
// 130.861 us; speedup vs baseline: 1.9606x; 1.9606x over previous
//
#include <hip/hip_runtime.h>
#include <hip/hip_bf16.h>

// Problem constants
#define B 64
#define D 25000
#define K 16
#define H 128
#define E 256
#define Z 32
#define DTILE 10
#define NBLK (D / DTILE)     // 2500 blocks
#define NREP 16              // replica accumulators (64 KB hot -> line-resident)
#define XSTR 65
#define MSTR 68

// ws layout: rep f32[NREP*B*K] | hi f16[H*K] (pad 4KB) | G f32[D*H]
#define REP_BYTES (NREP * B * K * 4)          // 65536
#define HI_OFF    REP_BYTES
#define G_OFF     (REP_BYTES + 4096)
#define WS_NEEDED (G_OFF + (size_t)D * H * 4) // ~12.9 MB

typedef __attribute__((ext_vector_type(8))) _Float16 half8;
typedef __attribute__((ext_vector_type(4))) float f32x4;
typedef __attribute__((ext_vector_type(2))) float f32x2;

// packed f32 fma (exists on gfx950; packed f32 max does NOT)
__device__ __forceinline__ f32x2 pk_fma(f32x2 a, f32x2 b, f32x2 c) {
    f32x2 d;
    asm("v_pk_fma_f32 %0, %1, %2, %3" : "=v"(d) : "v"(a), "v"(b), "v"(c));
    return d;
}
// packed f32->f16 (RTZ), returned as dword
__device__ __forceinline__ unsigned pkrtz_u(float a, float b) {
    auto h = __builtin_amdgcn_cvt_pkrtz(a, b);
    union { decltype(h) h; unsigned u; } c;
    c.h = h;
    return c.u;
}

// prep: blocks 0..15 zero replicas; block 16 builds fragment-ordered fp16 W2 table;
// blocks 17.. compute G[d][h] = feat_emb[d]@W1[1:17] + feat_bias[d]*W1[17] + b1  (if ws allows)
__global__ __launch_bounds__(256) void prep_kernel(
    const float* __restrict__ W2, const float* __restrict__ feat_emb,
    const float* __restrict__ feat_bias, const float* __restrict__ W1,
    const float* __restrict__ b1, float* __restrict__ rep,
    _Float16* __restrict__ hi, float* __restrict__ G)
{
    const int t = threadIdx.x;
    const int bid = blockIdx.x;
    if (bid < NREP) {
        for (int i = t; i < B * K; i += 256) rep[bid * B * K + i] = 0.f;
    } else if (bid == NREP) {
        for (int i = t; i < H * K; i += 256) {
            // i = ((s*4+g)*16+n)*8+j  ->  W2[(s*32+g*8+j)][n]
            int j = i & 7, n = (i >> 3) & 15, g = (i >> 7) & 3, s = i >> 9;
            int k = s * 32 + g * 8 + j;
            hi[i] = (_Float16)W2[k * K + n];
        }
    } else {
        int idx = (bid - NREP - 1) * 256 + t;   // < D*H by grid construction
        int d = idx >> 7, h = idx & (H - 1);
        float acc = fmaf(feat_bias[d], W1[17 * H + h], b1[h]);
        #pragma unroll
        for (int k = 0; k < K; ++k)
            acc = fmaf(feat_emb[d * K + k], W1[(1 + k) * H + h], acc);
        G[idx] = acc;
    }
}

// main: h1 = relu(x*w0 + G_d) [packed fma + v_max], h2 = relu(h1@W2 + b2) [fp16 MFMA, b2 in C-init],
// c += mask*h2 [fp32, replica atomics to hot lines]
template <bool PRE>
__global__ __launch_bounds__(256, 6) void partial_main_kernel(
    const float* __restrict__ x, const int* __restrict__ mask,
    const float* __restrict__ feat_emb, const float* __restrict__ feat_bias,
    const float* __restrict__ W1, const float* __restrict__ b1,
    const float* __restrict__ b2, const float* __restrict__ Gbuf,
    const _Float16* __restrict__ hi, float* __restrict__ rep)
{
    __shared__ __align__(16) float sG[DTILE * H];     // 5 KB
    __shared__ __align__(16) float sX[DTILE * XSTR];
    __shared__ __align__(16) float sMf[DTILE * MSTR];

    const int t    = threadIdx.x;
    const int d0   = blockIdx.x * DTILE;
    const int lane = t & 63;
    const int wv   = t >> 6;
    const int g    = lane >> 4;
    const int n    = lane & 15;

    // stage x/mask transposed
    for (int i = t; i < DTILE * B; i += 256) {
        int bb = i / DTILE, dd = i - bb * DTILE;
        sX[dd * XSTR + bb]  = x[bb * D + d0 + dd];
        sMf[dd * MSTR + bb] = (float)mask[bb * D + d0 + dd];
    }
    if (PRE) {
        // G tile staged from precomputed global buffer, coalesced float4
        const float4* gp = (const float4*)(Gbuf + d0 * H);
        float4* sg4 = (float4*)sG;
        for (int i = t; i < DTILE * H / 4; i += 256) sg4[i] = gp[i];
    } else {
        for (int i = t; i < DTILE * H; i += 256) {
            int dd = i >> 7, h = i & (H - 1);
            int d = d0 + dd;
            float acc = fmaf(feat_bias[d], W1[17 * H + h], b1[h]);
            #pragma unroll
            for (int k = 0; k < K; ++k)
                acc = fmaf(feat_emb[d * K + k], W1[(1 + k) * H + h], acc);
            sG[i] = acc;
        }
    }

    // per-lane W2 fp16 fragments (prepped, coalesced) + w0 pairs in regs
    half8 Bf[4];
    #pragma unroll
    for (int s = 0; s < 4; ++s)
        Bf[s] = *(const half8*)(hi + (((s * 4 + g) * 16 + n) << 3));
    f32x2 w0p[4][4];
    #pragma unroll
    for (int s = 0; s < 4; ++s) {
        const float4* wp = (const float4*)&W1[s * 32 + g * 8];
        float4 a0 = wp[0], a1 = wp[1];
        w0p[s][0] = (f32x2){a0.x, a0.y}; w0p[s][1] = (f32x2){a0.z, a0.w};
        w0p[s][2] = (f32x2){a1.x, a1.y}; w0p[s][3] = (f32x2){a1.z, a1.w};
    }
    const float b2n = b2[n];
    __syncthreads();

    f32x4 cacc = {0.f, 0.f, 0.f, 0.f};
    const int xoff = wv * 16 + n;
    const int moff = wv * 16 + g * 4;

    for (int dd = 0; dd < DTILE; ++dd) {
        const float xv = sX[dd * XSTR + xoff];
        const f32x2 xv2 = {xv, xv};
        f32x4 c1 = {b2n, b2n, b2n, b2n};
        #pragma unroll
        for (int s = 0; s < 4; ++s) {
            const float4* gp = (const float4*)&sG[dd * H + s * 32 + g * 8];
            const float4 ga = gp[0], gb = gp[1];
            f32x2 t0 = pk_fma(xv2, w0p[s][0], (f32x2){ga.x, ga.y});
            f32x2 t1 = pk_fma(xv2, w0p[s][1], (f32x2){ga.z, ga.w});
            f32x2 t2 = pk_fma(xv2, w0p[s][2], (f32x2){gb.x, gb.y});
            f32x2 t3 = pk_fma(xv2, w0p[s][3], (f32x2){gb.z, gb.w});
            union { half8 v; unsigned u[4]; } af;
            af.u[0] = pkrtz_u(fmaxf(t0.x, 0.f), fmaxf(t0.y, 0.f));
            af.u[1] = pkrtz_u(fmaxf(t1.x, 0.f), fmaxf(t1.y, 0.f));
            af.u[2] = pkrtz_u(fmaxf(t2.x, 0.f), fmaxf(t2.y, 0.f));
            af.u[3] = pkrtz_u(fmaxf(t3.x, 0.f), fmaxf(t3.y, 0.f));
            c1 = __builtin_amdgcn_mfma_f32_16x16x32_f16(af.v, Bf[s], c1, 0, 0, 0);
        }
        const float4 mv = *(const float4*)&sMf[dd * MSTR + moff];
        cacc[0] = fmaf(mv.x, fmaxf(c1[0], 0.f), cacc[0]);
        cacc[1] = fmaf(mv.y, fmaxf(c1[1], 0.f), cacc[1]);
        cacc[2] = fmaf(mv.z, fmaxf(c1[2], 0.f), cacc[2]);
        cacc[3] = fmaf(mv.w, fmaxf(c1[3], 0.f), cacc[3]);
    }

    float* crep = rep + (size_t)(blockIdx.x & (NREP - 1)) * (B * K);
    #pragma unroll
    for (int r = 0; r < 4; ++r)
        atomicAdd(&crep[(moff + r) * K + n], cacc[r]);
}

// enc: reduce NREP replicas -> c[b], then 16->256->64 MLP. one block per sample.
__global__ __launch_bounds__(256) void partial_enc_kernel(
    const float* __restrict__ rep, const float* __restrict__ We1,
    const float* __restrict__ be1, const float* __restrict__ We2,
    const float* __restrict__ be2, float* __restrict__ out)
{
    const int b = blockIdx.x;
    const int t = threadIdx.x;
    __shared__ float sc[K];
    __shared__ float st1[E];
    __shared__ float red[256];

    {   // replica reduction: thread (grp=t>>4, k=t&15) reads replica grp
        const int k = t & 15, grp = t >> 4;
        red[t] = rep[grp * (B * K) + b * K + k];
    }
    __syncthreads();
    if (t < K) {
        float s2 = 0.f;
        #pragma unroll
        for (int q = 0; q < 16; ++q) s2 += red[q * 16 + t];
        sc[t] = s2;
    }
    __syncthreads();

    {
        float acc = be1[t];
        #pragma unroll
        for (int k = 0; k < K; ++k)
            acc = fmaf(sc[k], We1[k * E + t], acc);
        st1[t] = fmaxf(acc, 0.f);
    }
    __syncthreads();

    const int j = t & 63, seg = t >> 6;
    float acc = 0.f;
    #pragma unroll 4
    for (int e = seg * 64; e < seg * 64 + 64; ++e)
        acc = fmaf(st1[e], We2[e * 64 + j], acc);
    red[t] = acc;
    __syncthreads();

    if (t < 64) {
        float v = red[j] + red[64 + j] + red[128 + j] + red[192 + j] + be2[j];
        if (j < Z) out[b * Z + j] = v;                 // mu
        else       out[B * Z + b * Z + (j - Z)] = v;   // logvar
    }
}

extern "C" void kernel_launch(void* const* d_in, const int* in_sizes, int n_in,
                              void* d_out, int out_size, void* d_ws, size_t ws_size,
                              hipStream_t stream) {
    const float* x         = (const float*)d_in[0];
    const int*   mask      = (const int*)  d_in[1];
    const float* feat_emb  = (const float*)d_in[2];
    const float* feat_bias = (const float*)d_in[3];
    const float* W1        = (const float*)d_in[4];
    const float* b1        = (const float*)d_in[5];
    const float* W2        = (const float*)d_in[6];
    const float* b2        = (const float*)d_in[7];
    const float* We1       = (const float*)d_in[8];
    const float* be1       = (const float*)d_in[9];
    const float* We2       = (const float*)d_in[10];
    const float* be2       = (const float*)d_in[11];

    float*     rep = (float*)d_ws;
    _Float16*  hi  = (_Float16*)((char*)d_ws + HI_OFF);
    float*     G   = (float*)((char*)d_ws + G_OFF);

    const bool big = (ws_size >= WS_NEEDED);   // constant across calls
    const int  gblocks = big ? (D * H / 256) : 0;

    prep_kernel<<<NREP + 1 + gblocks, 256, 0, stream>>>(
        W2, feat_emb, feat_bias, W1, b1, rep, hi, G);
    if (big)
        partial_main_kernel<true><<<NBLK, 256, 0, stream>>>(
            x, mask, feat_emb, feat_bias, W1, b1, b2, G, hi, rep);
    else
        partial_main_kernel<false><<<NBLK, 256, 0, stream>>>(
            x, mask, feat_emb, feat_bias, W1, b1, b2, G, hi, rep);
    partial_enc_kernel<<<B, 256, 0, stream>>>(
        rep, We1, be1, We2, be2, (float*)d_out);
}

// Round 7
// 122.705 us; speedup vs baseline: 2.0909x; 1.0665x over previous
//
#include <hip/hip_runtime.h>
#include <hip/hip_bf16.h>

// Problem constants
#define B 64
#define D 25000
#define K 16
#define H 128
#define E 256
#define Z 32
#define DTILE 10
#define NBLK (D / DTILE)     // 2500 blocks
#define NREP 16              // replica accumulators (64 KB hot -> line-resident)
#define XSTR 65
#define MSTR 68

// ws layout: rep f32[NREP*B*K] | hi f16[H*K] (pad 4KB) | Gh f16[D*H]
#define REP_BYTES (NREP * B * K * 4)          // 65536
#define HI_OFF    REP_BYTES
#define G_OFF     (REP_BYTES + 4096)
#define WS_NEEDED (G_OFF + (size_t)D * H * 2) // ~6.5 MB

typedef __attribute__((ext_vector_type(8))) _Float16 half8;
typedef __attribute__((ext_vector_type(2))) _Float16 hv2;
typedef __attribute__((ext_vector_type(4))) float f32x4;

// prep: blocks 0..15 zero replicas; block 16 builds fragment-ordered fp16 W2 table;
// blocks 17.. compute Gh[d][h] = fp16(feat_emb[d]@W1[1:17] + feat_bias[d]*W1[17] + b1)
__global__ __launch_bounds__(256) void prep_kernel(
    const float* __restrict__ W2, const float* __restrict__ feat_emb,
    const float* __restrict__ feat_bias, const float* __restrict__ W1,
    const float* __restrict__ b1, float* __restrict__ rep,
    _Float16* __restrict__ hi, _Float16* __restrict__ Gh)
{
    const int t = threadIdx.x;
    const int bid = blockIdx.x;
    if (bid < NREP) {
        for (int i = t; i < B * K; i += 256) rep[bid * B * K + i] = 0.f;
    } else if (bid == NREP) {
        for (int i = t; i < H * K; i += 256) {
            // i = ((s*4+g)*16+n)*8+j  ->  W2[(s*32+g*8+j)][n]
            int j = i & 7, n = (i >> 3) & 15, g = (i >> 7) & 3, s = i >> 9;
            int k = s * 32 + g * 8 + j;
            hi[i] = (_Float16)W2[k * K + n];
        }
    } else {
        int idx = (bid - NREP - 1) * 256 + t;   // < D*H by grid construction
        int d = idx >> 7, h = idx & (H - 1);
        float acc = fmaf(feat_bias[d], W1[17 * H + h], b1[h]);
        #pragma unroll
        for (int k = 0; k < K; ++k)
            acc = fmaf(feat_emb[d * K + k], W1[(1 + k) * H + h], acc);
        Gh[idx] = (_Float16)acc;
    }
}

// main: h1 = relu(x*w0 + G_d) in packed fp16 -> fp16 MFMA (b2 in C-init) ->
// c += mask * relu(.) in fp32, replica atomics. Two dd chains in flight for ILP.
template <bool PRE>
__global__ __launch_bounds__(256, 6) void partial_main_kernel(
    const float* __restrict__ x, const int* __restrict__ mask,
    const float* __restrict__ feat_emb, const float* __restrict__ feat_bias,
    const float* __restrict__ W1, const float* __restrict__ b1,
    const float* __restrict__ b2, const _Float16* __restrict__ Gh,
    const _Float16* __restrict__ hi, float* __restrict__ rep)
{
    __shared__ __align__(16) _Float16 sGh[DTILE * H];   // 2.5 KB
    __shared__ __align__(16) float sX[DTILE * XSTR];
    __shared__ __align__(16) float sMf[DTILE * MSTR];

    const int t    = threadIdx.x;
    const int d0   = blockIdx.x * DTILE;
    const int lane = t & 63;
    const int wv   = t >> 6;
    const int g    = lane >> 4;
    const int n    = lane & 15;

    // stage x/mask transposed
    for (int i = t; i < DTILE * B; i += 256) {
        int bb = i / DTILE, dd = i - bb * DTILE;
        sX[dd * XSTR + bb]  = x[bb * D + d0 + dd];
        sMf[dd * MSTR + bb] = (float)mask[bb * D + d0 + dd];
    }
    if (PRE) {
        // stage fp16 G tile, coalesced dword copy
        const unsigned* gsrc = (const unsigned*)(Gh + (size_t)d0 * H);
        unsigned* gdst = (unsigned*)sGh;
        for (int i = t; i < DTILE * H / 2; i += 256) gdst[i] = gsrc[i];
    } else {
        for (int i = t; i < DTILE * H; i += 256) {
            int dd = i >> 7, h = i & (H - 1);
            int d = d0 + dd;
            float acc = fmaf(feat_bias[d], W1[17 * H + h], b1[h]);
            #pragma unroll
            for (int k = 0; k < K; ++k)
                acc = fmaf(feat_emb[d * K + k], W1[(1 + k) * H + h], acc);
            sGh[i] = (_Float16)acc;
        }
    }

    // per-lane W2 fp16 fragments (prepped, coalesced) + w0 as fp16 pairs in regs
    half8 Bf[4];
    #pragma unroll
    for (int s = 0; s < 4; ++s)
        Bf[s] = *(const half8*)(hi + (((s * 4 + g) * 16 + n) << 3));
    hv2 w0h[4][4];
    #pragma unroll
    for (int s = 0; s < 4; ++s) {
        const float4* wp = (const float4*)&W1[s * 32 + g * 8];
        float4 a0 = wp[0], a1 = wp[1];
        w0h[s][0] = (hv2){(_Float16)a0.x, (_Float16)a0.y};
        w0h[s][1] = (hv2){(_Float16)a0.z, (_Float16)a0.w};
        w0h[s][2] = (hv2){(_Float16)a1.x, (_Float16)a1.y};
        w0h[s][3] = (hv2){(_Float16)a1.z, (_Float16)a1.w};
    }
    const float b2n = b2[n];
    const hv2 zeroh = {(_Float16)0.f, (_Float16)0.f};
    __syncthreads();

    f32x4 cacc = {0.f, 0.f, 0.f, 0.f};
    const int xoff = wv * 16 + n;
    const int moff = wv * 16 + g * 4;

    #pragma unroll
    for (int i = 0; i < DTILE / 2; ++i) {
        const int dd0 = 2 * i, dd1 = 2 * i + 1;
        const float xv0 = sX[dd0 * XSTR + xoff];
        const float xv1 = sX[dd1 * XSTR + xoff];
        const _Float16 xh0 = (_Float16)xv0, xh1 = (_Float16)xv1;
        const hv2 xa = {xh0, xh0}, xb = {xh1, xh1};
        f32x4 c1a = {b2n, b2n, b2n, b2n};
        f32x4 c1b = {b2n, b2n, b2n, b2n};
        #pragma unroll
        for (int s = 0; s < 4; ++s) {
            union GA { half8 v; hv2 p[4]; };
            GA ga, gb, A0, A1;
            ga.v = *(const half8*)&sGh[dd0 * H + s * 32 + g * 8];   // 1x ds_read_b128
            gb.v = *(const half8*)&sGh[dd1 * H + s * 32 + g * 8];
            #pragma unroll
            for (int p = 0; p < 4; ++p) {
                hv2 h0 = __builtin_elementwise_fma(xa, w0h[s][p], ga.p[p]);
                hv2 h1 = __builtin_elementwise_fma(xb, w0h[s][p], gb.p[p]);
                A0.p[p] = __builtin_elementwise_max(h0, zeroh);
                A1.p[p] = __builtin_elementwise_max(h1, zeroh);
            }
            c1a = __builtin_amdgcn_mfma_f32_16x16x32_f16(A0.v, Bf[s], c1a, 0, 0, 0);
            c1b = __builtin_amdgcn_mfma_f32_16x16x32_f16(A1.v, Bf[s], c1b, 0, 0, 0);
        }
        const float4 mv0 = *(const float4*)&sMf[dd0 * MSTR + moff];
        const float4 mv1 = *(const float4*)&sMf[dd1 * MSTR + moff];
        cacc[0] = fmaf(mv0.x, fmaxf(c1a[0], 0.f), fmaf(mv1.x, fmaxf(c1b[0], 0.f), cacc[0]));
        cacc[1] = fmaf(mv0.y, fmaxf(c1a[1], 0.f), fmaf(mv1.y, fmaxf(c1b[1], 0.f), cacc[1]));
        cacc[2] = fmaf(mv0.z, fmaxf(c1a[2], 0.f), fmaf(mv1.z, fmaxf(c1b[2], 0.f), cacc[2]));
        cacc[3] = fmaf(mv0.w, fmaxf(c1a[3], 0.f), fmaf(mv1.w, fmaxf(c1b[3], 0.f), cacc[3]));
    }

    float* crep = rep + (size_t)(blockIdx.x & (NREP - 1)) * (B * K);
    #pragma unroll
    for (int r = 0; r < 4; ++r)
        atomicAdd(&crep[(moff + r) * K + n], cacc[r]);
}

// enc: reduce NREP replicas -> c[b], then 16->256->64 MLP. one block per sample.
__global__ __launch_bounds__(256) void partial_enc_kernel(
    const float* __restrict__ rep, const float* __restrict__ We1,
    const float* __restrict__ be1, const float* __restrict__ We2,
    const float* __restrict__ be2, float* __restrict__ out)
{
    const int b = blockIdx.x;
    const int t = threadIdx.x;
    __shared__ float sc[K];
    __shared__ float st1[E];
    __shared__ float red[256];

    {   // replica reduction: thread (grp=t>>4, k=t&15) reads replica grp
        const int k = t & 15, grp = t >> 4;
        red[t] = rep[grp * (B * K) + b * K + k];
    }
    __syncthreads();
    if (t < K) {
        float s2 = 0.f;
        #pragma unroll
        for (int q = 0; q < 16; ++q) s2 += red[q * 16 + t];
        sc[t] = s2;
    }
    __syncthreads();

    {
        float acc = be1[t];
        #pragma unroll
        for (int k = 0; k < K; ++k)
            acc = fmaf(sc[k], We1[k * E + t], acc);
        st1[t] = fmaxf(acc, 0.f);
    }
    __syncthreads();

    const int j = t & 63, seg = t >> 6;
    float acc = 0.f;
    #pragma unroll 4
    for (int e = seg * 64; e < seg * 64 + 64; ++e)
        acc = fmaf(st1[e], We2[e * 64 + j], acc);
    red[t] = acc;
    __syncthreads();

    if (t < 64) {
        float v = red[j] + red[64 + j] + red[128 + j] + red[192 + j] + be2[j];
        if (j < Z) out[b * Z + j] = v;                 // mu
        else       out[B * Z + b * Z + (j - Z)] = v;   // logvar
    }
}

extern "C" void kernel_launch(void* const* d_in, const int* in_sizes, int n_in,
                              void* d_out, int out_size, void* d_ws, size_t ws_size,
                              hipStream_t stream) {
    const float* x         = (const float*)d_in[0];
    const int*   mask      = (const int*)  d_in[1];
    const float* feat_emb  = (const float*)d_in[2];
    const float* feat_bias = (const float*)d_in[3];
    const float* W1        = (const float*)d_in[4];
    const float* b1        = (const float*)d_in[5];
    const float* W2        = (const float*)d_in[6];
    const float* b2        = (const float*)d_in[7];
    const float* We1       = (const float*)d_in[8];
    const float* be1       = (const float*)d_in[9];
    const float* We2       = (const float*)d_in[10];
    const float* be2       = (const float*)d_in[11];

    float*     rep = (float*)d_ws;
    _Float16*  hi  = (_Float16*)((char*)d_ws + HI_OFF);
    _Float16*  Gh  = (_Float16*)((char*)d_ws + G_OFF);

    const bool big = (ws_size >= WS_NEEDED);   // constant across calls
    const int  gblocks = big ? (D * H / 256) : 0;

    prep_kernel<<<NREP + 1 + gblocks, 256, 0, stream>>>(
        W2, feat_emb, feat_bias, W1, b1, rep, hi, Gh);
    if (big)
        partial_main_kernel<true><<<NBLK, 256, 0, stream>>>(
            x, mask, feat_emb, feat_bias, W1, b1, b2, Gh, hi, rep);
    else
        partial_main_kernel<false><<<NBLK, 256, 0, stream>>>(
            x, mask, feat_emb, feat_bias, W1, b1, b2, Gh, hi, rep);
    partial_enc_kernel<<<B, 256, 0, stream>>>(
        rep, We1, be1, We2, be2, (float*)d_out);
}